// Round 4
// baseline (922.725 us; speedup 1.0000x reference)
//
#include <hip/hip_runtime.h>
#include <math.h>

// ============================================================================
// MoE FFN (dense, E=8): y = sum_e softmax(x@Wr)[:,e] * (gelu(x@W1_e+b1_e)@W2_e+b2_e)
// T=2048, D=1024, H=4096, E=8. FP32 in/out; bf16 MFMA compute.
// R7 -> R8: transconv kernels ELIMINATED. GEMMs consume fp32 weights [K][N]
// directly via reg-staged transpose-convert of B (T14): per K-tile, 4
// n-quarters; quarter j loaded at phase j (8 scalar f32 loads, 256B/wave
// contiguous), converted + written at phase j+2 as ONE ds_write_b128 into the
// dbuf B layout. B swizzle f(n)=(n&7)^((n>>3)&7): injective mod 8 on write
// beats (consecutive rows) AND read beats -> conflict-free both sides.
// Counted waits vmcnt(8/10/10/8), no vmcnt at tile end (loads span tiles).
// bq regs: 2x8 fp32 in flight (2-phase latency cover ~1200cyc > 900 HBM).
// A path (GLL16, chunk^(row&7)), 4-phase MM skeleton, epilogues: unchanged
// from R7 (verified). ws: P|accb|xb|Hs; tiers A >=147MB, B >=29.5MB, D zero.
// ============================================================================

typedef float f32x4 __attribute__((ext_vector_type(4)));
typedef __bf16 bf16x8 __attribute__((ext_vector_type(8)));

#define GLL16(gp, lp)                                                          \
  __builtin_amdgcn_global_load_lds(                                            \
      (const __attribute__((address_space(1))) void*)(gp),                     \
      (__attribute__((address_space(3))) void*)(lp), 16, 0, 0)

// Branch-free GELU: erf via Abramowitz-Stegun 7.1.26 (|err| <= 1.5e-7).
__device__ __forceinline__ float gelu_f(float h) {
  float x = h * 0.70710678118654752f;
  float ax = fabsf(x);
  float t = __builtin_amdgcn_rcpf(fmaf(0.3275911f, ax, 1.0f));
  float p = fmaf(1.061405429f, t, -1.453152027f);
  p = fmaf(p, t, 1.421413741f);
  p = fmaf(p, t, -0.284496736f);
  p = fmaf(p, t, 0.254829592f);
  float e = __expf(-x * x);
  float erfv = fmaf(-p * t, e, 1.0f);
  erfv = copysignf(erfv, x);
  return 0.5f * h * (1.0f + erfv);
}

// ---------------------------------------------------------------------------
// Router: logits = x @ rw + rb (fp32), softmax -> P (ws) + probs_out (d_out)
// ---------------------------------------------------------------------------
__global__ void router_kernel(const float* __restrict__ x,
                              const float* __restrict__ rw,
                              const float* __restrict__ rb,
                              float* __restrict__ P,
                              float* __restrict__ probs_out)
{
  int gid = blockIdx.x * blockDim.x + threadIdx.x;
  int t = gid >> 6;
  int l = gid & 63;
  const float* xr = x + (size_t)t * 1024;
  float a[8];
#pragma unroll
  for (int e = 0; e < 8; ++e) a[e] = 0.f;
  for (int d = l; d < 1024; d += 64) {
    float xv = xr[d];
    f32x4 w0 = *(const f32x4*)(rw + d * 8);
    f32x4 w1 = *(const f32x4*)(rw + d * 8 + 4);
#pragma unroll
    for (int e = 0; e < 4; ++e) a[e] += xv * w0[e];
#pragma unroll
    for (int e = 0; e < 4; ++e) a[4 + e] += xv * w1[e];
  }
#pragma unroll
  for (int off = 32; off > 0; off >>= 1) {
#pragma unroll
    for (int e = 0; e < 8; ++e) a[e] += __shfl_down(a[e], off);
  }
  if (l == 0) {
#pragma unroll
    for (int e = 0; e < 8; ++e) a[e] += rb[e];
    float m = a[0];
#pragma unroll
    for (int e = 1; e < 8; ++e) m = fmaxf(m, a[e]);
    float s = 0.f;
#pragma unroll
    for (int e = 0; e < 8; ++e) { a[e] = __expf(a[e] - m); s += a[e]; }
    float inv = 1.f / s;
#pragma unroll
    for (int e = 0; e < 8; ++e) {
      float p = a[e] * inv;
      if (P) P[t * 8 + e] = p;
      probs_out[t * 8 + e] = p;
    }
  }
}

// ---------------------------------------------------------------------------
// Convert fp32 -> bf16 row-major (for x)
// ---------------------------------------------------------------------------
__global__ void cvt_kernel(const float* __restrict__ src,
                           __bf16* __restrict__ dst)
{
  size_t i = ((size_t)blockIdx.x * 256 + threadIdx.x) * 8;
  f32x4 v0 = *(const f32x4*)(src + i);
  f32x4 v1 = *(const f32x4*)(src + i + 4);
  bf16x8 o;
#pragma unroll
  for (int j = 0; j < 4; ++j) o[j] = (__bf16)v0[j];
#pragma unroll
  for (int j = 0; j < 4; ++j) o[4 + j] = (__bf16)v1[j];
  *(bf16x8*)(dst + i) = o;
}

// ---------------------------------------------------------------------------
// 4-phase 256x256 MFMA mainloop, BK=64. A: bf16 [M][K] via GLL16 (dbuf,
// chunk^(row&7) swizzle). B: fp32 [K][N] via reg-staged transpose-convert:
//   thread (w,l): k-rows w*8..w*8+7, n-cols {l, l+64, l+128, l+192}.
//   Quarter j: 8 scalar f32 loads (wave = 256B contiguous) at phase j,
//   bf16x8 ds_write_b128 at phase j+2 to row nn=j*64+l, chunk w^f(nn),
//   f(n)=(n&7)^((n>>3)&7) (conflict-free write+read beats).
// Per tile: quarters 2,3 of B(t+1) written at ph0/ph1 (loaded prev tile),
// quarters 0,1 of B(t+2) written at ph2/ph3 (loaded this tile ph0/ph1).
// Waits: vmcnt(8/10/10/8) at ph0..ph3 (2-phase latency cover); tile end
// lgkmcnt(0) only -- 16 loads stay in flight across the boundary (T4).
// LDS safety: a B(t) region is overwritten no earlier than ph2, after all
// waves' B(t) ds_reads completed (consumed by MM before ph0/ph1-end BARs).
// ---------------------------------------------------------------------------
__device__ __forceinline__ void mfma_loop256(
    const char* Ab, const float* Bf, size_t ldaB, int ldN, int K,
    char* lds, f32x4 acc[8][4])
{
  const int tid = threadIdx.x;
  const int w = tid >> 6, l = tid & 63;
  const int wm = w >> 2, wn = w & 3;
  const int m16 = l & 15, q = l >> 4;
  const int s1 = m16 & 7, s2 = m16 >> 3;
  const int aBase = wm * 16384 + m16 * 128;
  const int bRow = 32768 + (wn >> 1) * 16384 + ((wn & 1) * 64 + m16) * 128;
  // A stage-side (GLL16): lane covers rows w*16+(l>>3)+{0,8} per half,
  // LDS chunk (l&7) sourcing global chunk (l&7)^((l>>3)&7).
  const int srcCh = ((l & 7) ^ ((l >> 3) & 7)) << 4;
  const size_t gA0 = (size_t)(w * 16 + (l >> 3)) * ldaB + srcCh;
  const int dstW = w * 2048;
  // B stage-side
  const float* bThr = Bf + (size_t)(w * 8) * (size_t)ldN + l;
  const int bwBase = 32768 + l * 128 + ((w ^ ((l & 7) ^ ((l >> 3) & 7))) << 4);
  const int NT = K >> 6;

  float bq0[8], bq1[8];
  bf16x8 af[4][2], bv[4][2];

#define STG_A(h, tau)                                                          \
  {                                                                            \
    char* d = lds + (((tau) & 1) * 65536) + (h) * 16384 + dstW;                \
    const char* g = Ab + gA0 + (size_t)((h) * 128) * ldaB + (size_t)(tau) * 128;\
    GLL16(g, d);                                                               \
    GLL16(g + 8 * ldaB, d + 1024);                                             \
  }
#define BL_Q(arr, j, tau)                                                      \
  _Pragma("unroll") for (int kk = 0; kk < 8; ++kk)                             \
    arr[kk] = bThr[((size_t)(tau) * 64 + kk) * (size_t)ldN + (j) * 64];
#define BW_Q(arr, j, tau)                                                      \
  {                                                                            \
    bf16x8 vv;                                                                 \
    _Pragma("unroll") for (int kk = 0; kk < 8; ++kk) vv[kk] = (__bf16)arr[kk]; \
    *(bf16x8*)(lds + (((tau) & 1) * 65536) + bwBase + (j) * 8192) = vv;        \
  }
#define RD_A(lo, p)                                                            \
  _Pragma("unroll") for (int mi = 0; mi < 4; ++mi)                             \
  _Pragma("unroll") for (int ks = 0; ks < 2; ++ks)                             \
    af[mi][ks] = *(const bf16x8*)(lds + (p) * 65536 + aBase +                  \
        ((lo) * 4 + mi) * 2048 + (((ks * 4 + q) ^ s1) << 4));
#define RD_B(no, p)                                                            \
  _Pragma("unroll") for (int nj = 0; nj < 2; ++nj) {                           \
    const int fB = s1 ^ ((((no) * 2 + nj) * 2 + s2) & 7);                      \
    _Pragma("unroll") for (int ks = 0; ks < 2; ++ks)                           \
      bv[(no) * 2 + nj][ks] = *(const bf16x8*)(lds + (p) * 65536 + bRow +      \
          ((no) * 2 + nj) * 2048 + (((ks * 4 + q) ^ fB) << 4));                \
  }
#define MM(lo, no)                                                             \
  __builtin_amdgcn_s_setprio(1);                                               \
  _Pragma("unroll") for (int mi = 0; mi < 4; ++mi)                             \
  _Pragma("unroll") for (int nj = 0; nj < 2; ++nj)                             \
  _Pragma("unroll") for (int ks = 0; ks < 2; ++ks)                             \
    acc[(lo) * 4 + mi][(no) * 2 + nj] =                                        \
        __builtin_amdgcn_mfma_f32_16x16x32_bf16(                               \
            af[mi][ks], bv[(no) * 2 + nj][ks],                                 \
            acc[(lo) * 4 + mi][(no) * 2 + nj], 0, 0, 0);                       \
  __builtin_amdgcn_s_setprio(0);
#define SB __builtin_amdgcn_sched_barrier(0)
#define BAR { SB; __builtin_amdgcn_s_barrier(); SB; }
#define VMW(n) asm volatile("s_waitcnt vmcnt(" #n ")" ::: "memory")
#define LKW0 asm volatile("s_waitcnt lgkmcnt(0)" ::: "memory")

  // Prologue: A(0) via GLL; B(0) all quarters; B(1) q0,q1 written, q2,q3
  // left in flight (consumed at t=0 ph0/ph1). Ends with 16 loads outstanding.
  STG_A(0, 0); STG_A(1, 0);
  BL_Q(bq0, 0, 0); BL_Q(bq1, 1, 0);
  VMW(0);
  BW_Q(bq0, 0, 0); BW_Q(bq1, 1, 0);
  BL_Q(bq0, 2, 0); BL_Q(bq1, 3, 0);
  VMW(0);
  BW_Q(bq0, 2, 0); BW_Q(bq1, 3, 0);
  BL_Q(bq0, 0, 1); BL_Q(bq1, 1, 1);
  VMW(0);
  BW_Q(bq0, 0, 1); BW_Q(bq1, 1, 1);
  BL_Q(bq0, 2, 1); BL_Q(bq1, 3, 1);
  LKW0;
  BAR;

  int t = 0;
  for (; t < NT - 2; ++t) {
    const int p = t & 1;
    // ph0: outstanding 16 (prev ph2 + ph3); drain prev-ph2 -> bq0 ready
    RD_A(0, p); RD_B(0, p);
    VMW(8);
    BW_Q(bq0, 2, t + 1);
    BL_Q(bq0, 0, t + 2);
    STG_A(0, t + 1);
    BAR; MM(0, 0); BAR;
    // ph1: outstanding 18; drain prev-ph3 -> bq1 ready
    RD_B(1, p);
    VMW(10);
    BW_Q(bq1, 3, t + 1);
    BL_Q(bq1, 1, t + 2);
    STG_A(1, t + 1);
    BAR; MM(0, 1); BAR;
    // ph2: outstanding 20; drain ph0 group (bq0 + A0)
    RD_A(1, p);
    VMW(10);
    BW_Q(bq0, 0, t + 2);
    BL_Q(bq0, 2, t + 2);
    BAR; MM(1, 0); BAR;
    // ph3: outstanding 18; drain ph1 group (bq1 + A1)
    VMW(8);
    BW_Q(bq1, 1, t + 2);
    BL_Q(bq1, 3, t + 2);
    BAR; MM(1, 1); SB;
    LKW0;           // ds_writes visible; 16 loads stay in flight
    BAR;
  }
  {  // t = NT-2: finish B(NT-1) q2,q3; stage A(NT-1); drain fully
    const int p = t & 1;
    RD_A(0, p); RD_B(0, p);
    VMW(8);
    BW_Q(bq0, 2, t + 1);
    STG_A(0, t + 1);
    BAR; MM(0, 0); BAR;
    RD_B(1, p);
    VMW(2);
    BW_Q(bq1, 3, t + 1);
    STG_A(1, t + 1);
    BAR; MM(0, 1); BAR;
    RD_A(1, p);
    BAR; MM(1, 0); BAR;
    MM(1, 1); SB;
    asm volatile("s_waitcnt vmcnt(0) lgkmcnt(0)" ::: "memory");
    BAR;
    ++t;
  }
  {  // t = NT-1: all resident, no stages -> no barriers
    const int p = t & 1;
    RD_A(0, p); RD_B(0, p);
    MM(0, 0);
    RD_B(1, p);
    MM(0, 1);
    RD_A(1, p);
    MM(1, 0);
    MM(1, 1);
  }
#undef STG_A
#undef BL_Q
#undef BW_Q
#undef RD_A
#undef RD_B
#undef MM
#undef SB
#undef BAR
#undef VMW
#undef LKW0
}

// bijective XCD-chunked block swizzle (nwg % 8 == 0 for all our grids)
__device__ __forceinline__ int xcd_swz(int id, int nwg) {
  return ((nwg & 7) == 0) ? ((id & 7) * (nwg >> 3) + (id >> 3)) : id;
}

// ---------------------------------------------------------------------------
// GEMM1: Hs[t, zcol+h] = P[t,e] * gelu(Xb @ W1_e + b1_e)   (bf16 store)
// B = W1 fp32 [K=1024][N=4096] consumed directly. grid (8, 16, Z), 512 thr.
// ---------------------------------------------------------------------------
__global__ __launch_bounds__(512, 2) void gemm1_kernel(
    const __bf16* __restrict__ X, const float* __restrict__ W1,
    const float* __restrict__ b1, const float* __restrict__ P,
    __bf16* __restrict__ Hs, int hs_ld, int e_off, size_t b_zstride)
{
  __shared__ __align__(16) char lds[131072];
  const int nwg = gridDim.x * gridDim.y * gridDim.z;
  const int id = blockIdx.x + gridDim.x * (blockIdx.y + gridDim.y * blockIdx.z);
  const int wg = xcd_swz(id, nwg);
  const int bm = wg & 7;
  const int bn = (wg >> 3) % gridDim.y;
  const int z = wg / (gridDim.y << 3);
  const int e = z + e_off;

  f32x4 acc[8][4];
  const f32x4 z4 = {0.f, 0.f, 0.f, 0.f};
#pragma unroll
  for (int i = 0; i < 8; ++i)
#pragma unroll
    for (int j = 0; j < 4; ++j) acc[i][j] = z4;

  const char* A = (const char*)(X + (size_t)bm * 256 * 1024);
  const float* Bf = W1 + (size_t)z * b_zstride + (size_t)bn * 256;
  mfma_loop256(A, Bf, 2048, 4096, 1024, lds, acc);

  const int tid = threadIdx.x, w = tid >> 6, l = tid & 63;
  const int wm = w >> 2, wn = w & 3, q = l >> 4, m16 = l & 15;
  const int row0 = bm * 256 + wm * 128 + q * 4;
  const int colE = bn * 256 + wn * 64 + m16;
  const int zcol = (hs_ld == 4096) ? 0 : z * 4096;
  float b1v[4];
#pragma unroll
  for (int nj = 0; nj < 4; ++nj)
    b1v[nj] = b1[(size_t)e * 4096 + colE + nj * 16];
#pragma unroll
  for (int mi = 0; mi < 8; ++mi) {
    float pv[4];
#pragma unroll
    for (int r = 0; r < 4; ++r)
      pv[r] = P[(size_t)(row0 + mi * 16 + r) * 8 + e];
#pragma unroll
    for (int nj = 0; nj < 4; ++nj)
#pragma unroll
      for (int r = 0; r < 4; ++r) {
        float h = acc[mi][nj][r] + b1v[nj];
        float o = gelu_f(h) * pv[r];
        Hs[(size_t)(row0 + mi * 16 + r) * hs_ld + zcol + colE + nj * 16] =
            (__bf16)o;
      }
  }
}

// ---------------------------------------------------------------------------
// GEMM2: accb[t,d] += Hs_chunk @ W2_chunk (split-K via z, fp32 atomics)
// B = W2 fp32 [K][N=1024] consumed directly. grid (8, 4, Z), 512 threads.
// ---------------------------------------------------------------------------
__global__ __launch_bounds__(512, 2) void gemm2_kernel(
    const __bf16* __restrict__ Hs, const float* __restrict__ W2,
    float* __restrict__ accb, int lda, size_t a_zoff, size_t b_zoff, int Kb)
{
  __shared__ __align__(16) char lds[131072];
  const int nwg = gridDim.x * gridDim.y * gridDim.z;
  const int id = blockIdx.x + gridDim.x * (blockIdx.y + gridDim.y * blockIdx.z);
  const int wg = xcd_swz(id, nwg);
  const int bm = wg & 7;
  const int bn = (wg >> 3) % gridDim.y;
  const int z = wg / (gridDim.y << 3);

  f32x4 acc[8][4];
  const f32x4 z4 = {0.f, 0.f, 0.f, 0.f};
#pragma unroll
  for (int i = 0; i < 8; ++i)
#pragma unroll
    for (int j = 0; j < 4; ++j) acc[i][j] = z4;

  const char* A = (const char*)(Hs + (size_t)bm * 256 * lda + (size_t)z * a_zoff);
  const float* Bf = W2 + (size_t)z * b_zoff + (size_t)bn * 256;
  mfma_loop256(A, Bf, (size_t)lda * 2, 1024, Kb, lds, acc);

  const int tid = threadIdx.x, w = tid >> 6, l = tid & 63;
  const int wm = w >> 2, wn = w & 3, q = l >> 4, m16 = l & 15;
  const int row0 = bm * 256 + wm * 128 + q * 4;
  const int col0 = bn * 256 + wn * 64 + m16;
#pragma unroll
  for (int mi = 0; mi < 8; ++mi)
#pragma unroll
    for (int nj = 0; nj < 4; ++nj)
#pragma unroll
      for (int r = 0; r < 4; ++r)
        unsafeAtomicAdd(
            accb + (size_t)(row0 + mi * 16 + r) * 1024 + col0 + nj * 16,
            acc[mi][nj][r]);
}

// ---------------------------------------------------------------------------
// Finalize: y = accb + sum_e P*b2   (fp32)
// ---------------------------------------------------------------------------
__global__ void finalize_kernel(const float* __restrict__ accb,
                                const float* __restrict__ P,
                                const float* __restrict__ b2,
                                float* __restrict__ y)
{
  int idx = blockIdx.x * 256 + threadIdx.x;
  int t = idx >> 8;
  int d0 = (idx & 255) << 2;
  f32x4 a = *(const f32x4*)(accb + (size_t)t * 1024 + d0);
#pragma unroll
  for (int e = 0; e < 8; ++e) {
    float p = P[t * 8 + e];
    f32x4 b = *(const f32x4*)(b2 + (size_t)e * 1024 + d0);
#pragma unroll
    for (int c = 0; c < 4; ++c) a[c] += p * b[c];
  }
  *(f32x4*)(y + (size_t)t * 1024 + d0) = a;
}

// ---------------------------------------------------------------------------
// Tier D: zero-workspace fused VALU fallback (fp32)
// ---------------------------------------------------------------------------
__global__ __launch_bounds__(256) void fused_naive_kernel(
    const float* __restrict__ x, const float* __restrict__ w1,
    const float* __restrict__ b1, const float* __restrict__ w2,
    const float* __restrict__ b2, const float* __restrict__ probs,
    float* __restrict__ y)
{
  __shared__ float xs[8][1024];
  __shared__ float gs[8][64];
  __shared__ float ps[8];
  const int tid = threadIdx.x;
  const int t0 = blockIdx.x * 8;
  const size_t DH = (size_t)1024 * 4096;
  const int tt = tid >> 5;
  const int d0 = (tid & 31) * 32;
  float acc[32];
#pragma unroll
  for (int i = 0; i < 32; ++i) acc[i] = 0.f;
  {
    const f32x4* xsrc = (const f32x4*)(x + (size_t)t0 * 1024);
    f32x4* xdst = (f32x4*)&xs[0][0];
    for (int i = tid; i < 2048; i += 256) xdst[i] = xsrc[i];
  }
  const int wv = tid >> 6;
  const int hl = tid & 63;
  for (int e = 0; e < 8; ++e) {
    if (tid < 8) ps[tid] = probs[(size_t)(t0 + tid) * 8 + e];
    __syncthreads();
    for (int hc = 0; hc < 4096; hc += 64) {
      float a0 = 0.f, a1 = 0.f;
      const float* w1p = w1 + (size_t)e * DH + hc + hl;
      for (int d = 0; d < 1024; ++d) {
        float wvv = w1p[(size_t)d * 4096];
        a0 += xs[wv * 2 + 0][d] * wvv;
        a1 += xs[wv * 2 + 1][d] * wvv;
      }
      __syncthreads();
      gs[wv * 2 + 0][hl] =
          ps[wv * 2 + 0] * gelu_f(a0 + b1[(size_t)e * 4096 + hc + hl]);
      gs[wv * 2 + 1][hl] =
          ps[wv * 2 + 1] * gelu_f(a1 + b1[(size_t)e * 4096 + hc + hl]);
      __syncthreads();
      const float* w2p = w2 + (size_t)e * DH + (size_t)hc * 1024 + d0;
      for (int hh = 0; hh < 64; ++hh) {
        float g = gs[tt][hh];
#pragma unroll
        for (int jb = 0; jb < 8; ++jb) {
          f32x4 w4 = *(const f32x4*)(w2p + (size_t)hh * 1024 + jb * 4);
#pragma unroll
          for (int j2 = 0; j2 < 4; ++j2) acc[jb * 4 + j2] += g * w4[j2];
        }
      }
    }
#pragma unroll
    for (int j = 0; j < 32; ++j)
      acc[j] += ps[tt] * b2[(size_t)e * 1024 + d0 + j];
    __syncthreads();
  }
  float* yp = y + (size_t)(t0 + tt) * 1024 + d0;
#pragma unroll
  for (int jb = 0; jb < 8; ++jb) {
    f32x4 o = {acc[jb * 4], acc[jb * 4 + 1], acc[jb * 4 + 2], acc[jb * 4 + 3]};
    *(f32x4*)(yp + jb * 4) = o;
  }
}

// ---------------------------------------------------------------------------
extern "C" void kernel_launch(void* const* d_in, const int* in_sizes, int n_in,
                              void* d_out, int out_size, void* d_ws,
                              size_t ws_size, hipStream_t stream)
{
  const float* x  = (const float*)d_in[0];  // [2048,1024]
  const float* rw = (const float*)d_in[1];  // [1024,8]
  const float* rb = (const float*)d_in[2];  // [8]
  const float* w1 = (const float*)d_in[3];  // [8,1024,4096]
  const float* b1 = (const float*)d_in[4];  // [8,4096]
  const float* w2 = (const float*)d_in[5];  // [8,4096,1024]
  const float* b2 = (const float*)d_in[6];  // [8,1024]
  float* y = (float*)d_out;                   // [2048,1024]
  float* probs_out = y + (size_t)2048 * 1024; // [2048,8]

  const size_t DH = (size_t)1024 * 4096;
  const size_t BASE = (64 << 10) + (size_t)2048 * 1024 * 4 +
                      (size_t)2048 * 1024 * 2;                 // P|accb|xb
  const size_t TA = BASE + (size_t)2048 * 32768 * 2;           // ~147 MB
  const size_t TB = BASE + (size_t)2048 * 4096 * 2;            // ~29.5 MB

  char* ws = (char*)d_ws;
  float* P = (float*)ws;
  float* accb = (float*)(ws + (64 << 10));
  __bf16* xb = (__bf16*)(ws + (64 << 10) + (size_t)2048 * 1024 * 4);
  __bf16* Hs = (__bf16*)(ws + BASE);

  if (ws_size >= TA) {
    router_kernel<<<512, 256, 0, stream>>>(x, rw, rb, P, probs_out);
    hipMemsetAsync(accb, 0, (size_t)2048 * 1024 * 4, stream);
    cvt_kernel<<<1024, 256, 0, stream>>>(x, xb);
    gemm1_kernel<<<dim3(8, 16, 8), 512, 0, stream>>>(xb, w1, b1, P, Hs,
                                                     32768, 0, DH);
    gemm2_kernel<<<dim3(8, 4, 8), 512, 0, stream>>>(Hs, w2, accb, 32768,
                                                    4096, DH, 4096);
    finalize_kernel<<<2048, 256, 0, stream>>>(accb, P, b2, y);
  } else if (ws_size >= TB) {
    router_kernel<<<512, 256, 0, stream>>>(x, rw, rb, P, probs_out);
    hipMemsetAsync(accb, 0, (size_t)2048 * 1024 * 4, stream);
    cvt_kernel<<<1024, 256, 0, stream>>>(x, xb);
    for (int e = 0; e < 8; ++e) {
      gemm1_kernel<<<dim3(8, 16, 1), 512, 0, stream>>>(
          xb, w1 + (size_t)e * DH, b1, P, Hs, 4096, e, 0);
      gemm2_kernel<<<dim3(8, 4, 4), 512, 0, stream>>>(
          Hs, w2 + (size_t)e * DH, accb, 4096, 1024,
          (size_t)1024 * 1024, 1024);
    }
    finalize_kernel<<<2048, 256, 0, stream>>>(accb, P, b2, y);
  } else {
    router_kernel<<<512, 256, 0, stream>>>(x, rw, rb, (float*)nullptr,
                                           probs_out);
    fused_naive_kernel<<<256, 256, 0, stream>>>(x, w1, b1, w2, b2, probs_out,
                                                y);
  }
}

// Round 5
// 609.382 us; speedup vs baseline: 1.5142x; 1.5142x over previous
//
#include <hip/hip_runtime.h>
#include <math.h>

// ============================================================================
// MoE FFN (dense, E=8): y = sum_e softmax(x@Wr)[:,e] * (gelu(x@W1_e+b1_e)@W2_e+b2_e)
// T=2048, D=1024, H=4096, E=8. FP32 in/out; bf16 MFMA compute.
// R8 -> R9: REVERT GEMM structure to verified R7/R3 state (4-phase BK=64
// dbuf, GLL16 both operands, chunk^(row&7) swizzle, vmcnt(4), setprio; 0
// bank conflicts, MfmaUtil 35%). R8's fused B-transpose collapsed perf
// (4.19M conflicts) -- withdrawn. New: dispatch-count reduction 8 -> 5:
// (1) pre_kernel fuses router + cvt(x->bf16) + y bias-init (y = sum_e P*b2);
// (2) gemm2 atomics go directly into y -> finalize + memset + accb deleted.
// ws: P | xb | WT | Hs. Tiers: A >=196.1MB, B >=28.1MB, D zero-ws fallback.
// ============================================================================

typedef float f32x4 __attribute__((ext_vector_type(4)));
typedef __bf16 bf16x8 __attribute__((ext_vector_type(8)));

#define GLL16(gp, lp)                                                          \
  __builtin_amdgcn_global_load_lds(                                            \
      (const __attribute__((address_space(1))) void*)(gp),                     \
      (__attribute__((address_space(3))) void*)(lp), 16, 0, 0)

// Branch-free GELU: erf via Abramowitz-Stegun 7.1.26 (|err| <= 1.5e-7).
__device__ __forceinline__ float gelu_f(float h) {
  float x = h * 0.70710678118654752f;
  float ax = fabsf(x);
  float t = __builtin_amdgcn_rcpf(fmaf(0.3275911f, ax, 1.0f));
  float p = fmaf(1.061405429f, t, -1.453152027f);
  p = fmaf(p, t, 1.421413741f);
  p = fmaf(p, t, -0.284496736f);
  p = fmaf(p, t, 0.254829592f);
  float e = __expf(-x * x);
  float erfv = fmaf(-p * t, e, 1.0f);
  erfv = copysignf(erfv, x);
  return 0.5f * h * (1.0f + erfv);
}

// ---------------------------------------------------------------------------
// pre_kernel: per row t -- router softmax (P + probs_out), x -> bf16 (xb),
// y bias-init y[t] = sum_e P[t,e]*b2[e].  grid 512 x 256 (4 rows/block,
// 64 lanes/row; lane l owns d = l*16..l*16+15).
// ---------------------------------------------------------------------------
__global__ void pre_kernel(const float* __restrict__ x,
                           const float* __restrict__ rw,
                           const float* __restrict__ rb,
                           const float* __restrict__ b2,
                           float* __restrict__ P,
                           float* __restrict__ probs_out,
                           __bf16* __restrict__ xb,
                           float* __restrict__ y)
{
  __shared__ float ps[4][8];
  const int tid = threadIdx.x;
  const int g = tid >> 6, l = tid & 63;
  const int t = blockIdx.x * 4 + g;
  const int d0 = l * 16;
  const float* xr = x + (size_t)t * 1024 + d0;

  f32x4 xv[4];
#pragma unroll
  for (int i = 0; i < 4; ++i) xv[i] = *(const f32x4*)(xr + i * 4);

  // cvt store (bf16x8 x2)
  {
    bf16x8 o0, o1;
#pragma unroll
    for (int j = 0; j < 8; ++j) {
      o0[j] = (__bf16)xv[j >> 2][j & 3];
      o1[j] = (__bf16)xv[2 + (j >> 2)][j & 3];
    }
    *(bf16x8*)(xb + (size_t)t * 1024 + d0) = o0;
    *(bf16x8*)(xb + (size_t)t * 1024 + d0 + 8) = o1;
  }

  // router partial dot over this lane's 16 d
  float a[8];
#pragma unroll
  for (int e = 0; e < 8; ++e) a[e] = 0.f;
#pragma unroll
  for (int i = 0; i < 16; ++i) {
    float xs = xv[i >> 2][i & 3];
    const float* wr = rw + (size_t)(d0 + i) * 8;
    f32x4 w0 = *(const f32x4*)(wr);
    f32x4 w1 = *(const f32x4*)(wr + 4);
#pragma unroll
    for (int e = 0; e < 4; ++e) a[e] = fmaf(xs, w0[e], a[e]);
#pragma unroll
    for (int e = 0; e < 4; ++e) a[4 + e] = fmaf(xs, w1[e], a[4 + e]);
  }
#pragma unroll
  for (int off = 32; off > 0; off >>= 1) {
#pragma unroll
    for (int e = 0; e < 8; ++e) a[e] += __shfl_down(a[e], off);
  }
  if (l == 0) {
#pragma unroll
    for (int e = 0; e < 8; ++e) a[e] += rb[e];
    float m = a[0];
#pragma unroll
    for (int e = 1; e < 8; ++e) m = fmaxf(m, a[e]);
    float s = 0.f;
#pragma unroll
    for (int e = 0; e < 8; ++e) { a[e] = __expf(a[e] - m); s += a[e]; }
    float inv = 1.f / s;
#pragma unroll
    for (int e = 0; e < 8; ++e) {
      float p = a[e] * inv;
      P[t * 8 + e] = p;
      probs_out[t * 8 + e] = p;
      ps[g][e] = p;
    }
  }
  __syncthreads();

  // y bias-init: y[t][d] = sum_e p[e]*b2[e][d]
  f32x4 acc[4];
#pragma unroll
  for (int i = 0; i < 4; ++i) acc[i] = {0.f, 0.f, 0.f, 0.f};
#pragma unroll
  for (int e = 0; e < 8; ++e) {
    float p = ps[g][e];
#pragma unroll
    for (int i = 0; i < 4; ++i) {
      f32x4 b = *(const f32x4*)(b2 + (size_t)e * 1024 + d0 + i * 4);
#pragma unroll
      for (int c = 0; c < 4; ++c) acc[i][c] = fmaf(p, b[c], acc[i][c]);
    }
  }
#pragma unroll
  for (int i = 0; i < 4; ++i)
    *(f32x4*)(y + (size_t)t * 1024 + d0 + i * 4) = acc[i];
}

// ---------------------------------------------------------------------------
// Router only (tier D): logits = x @ rw + rb, softmax -> probs_out
// ---------------------------------------------------------------------------
__global__ void router_kernel(const float* __restrict__ x,
                              const float* __restrict__ rw,
                              const float* __restrict__ rb,
                              float* __restrict__ probs_out)
{
  int gid = blockIdx.x * blockDim.x + threadIdx.x;
  int t = gid >> 6;
  int l = gid & 63;
  const float* xr = x + (size_t)t * 1024;
  float a[8];
#pragma unroll
  for (int e = 0; e < 8; ++e) a[e] = 0.f;
  for (int d = l; d < 1024; d += 64) {
    float xv = xr[d];
    f32x4 w0 = *(const f32x4*)(rw + d * 8);
    f32x4 w1 = *(const f32x4*)(rw + d * 8 + 4);
#pragma unroll
    for (int e = 0; e < 4; ++e) a[e] += xv * w0[e];
#pragma unroll
    for (int e = 0; e < 4; ++e) a[4 + e] += xv * w1[e];
  }
#pragma unroll
  for (int off = 32; off > 0; off >>= 1) {
#pragma unroll
    for (int e = 0; e < 8; ++e) a[e] += __shfl_down(a[e], off);
  }
  if (l == 0) {
#pragma unroll
    for (int e = 0; e < 8; ++e) a[e] += rb[e];
    float m = a[0];
#pragma unroll
    for (int e = 1; e < 8; ++e) m = fmaxf(m, a[e]);
    float s = 0.f;
#pragma unroll
    for (int e = 0; e < 8; ++e) { a[e] = __expf(a[e] - m); s += a[e]; }
    float inv = 1.f / s;
#pragma unroll
    for (int e = 0; e < 8; ++e) probs_out[t * 8 + e] = a[e] * inv;
  }
}

// ---------------------------------------------------------------------------
// LDS-tiled transpose+convert: src fp32 [z][R][C] -> dst bf16 dst[c][dstLd]
// (+ z*zOff element offset within row) holding src[r][c] at [c][... + r].
// 64x64 tiles, 256 threads. Coalesced reads and bf16x8 stores. LDS [64][65]:
// writes 2-way (free), reads conflict-free. Grid: (R/64, C/64, Z).
// ---------------------------------------------------------------------------
__global__ void transconv_kernel(const float* __restrict__ src,
                                 __bf16* __restrict__ dst,
                                 int R, int C, size_t dstLd, size_t zOff)
{
  __shared__ float tile[64][65];
  size_t bs = (size_t)blockIdx.z * (size_t)R * (size_t)C;
  size_t dzo = (size_t)blockIdx.z * zOff;
  int r0 = blockIdx.x * 64, c0 = blockIdx.y * 64;
  int tr = threadIdx.x >> 4;         // 0..15
  int tc = (threadIdx.x & 15) * 4;   // 0,4,..,60
#pragma unroll
  for (int i = 0; i < 4; ++i) {
    f32x4 v = *(const f32x4*)(src + bs + (size_t)(r0 + tr + 16 * i) * C + c0 + tc);
#pragma unroll
    for (int j = 0; j < 4; ++j) tile[tr + 16 * i][tc + j] = v[j];
  }
  __syncthreads();
  int oc = threadIdx.x >> 3;         // 0..31
  int orr = (threadIdx.x & 7) * 8;   // 0,8,..,56
#pragma unroll
  for (int i = 0; i < 2; ++i) {
    int c = oc + 32 * i;
    bf16x8 o;
#pragma unroll
    for (int j = 0; j < 8; ++j) o[j] = (__bf16)tile[orr + j][c];
    *(bf16x8*)(dst + (size_t)(c0 + c) * dstLd + dzo + r0 + orr) = o;
  }
}

// ---------------------------------------------------------------------------
// 4-phase 256x256 MFMA mainloop, BK=64 (verified R7 structure).
// 8 waves (wm=w>>2, wn=w&3), per-wave out 128x64 = 8x4 frags of 16x16x32,
// 64 MFMA / K-tile / wave in 4 quadrant phases of 16.
// LDS: buf p (p=t&1) at p*65536: A-half h (128 rows x 128B) at h*16384,
// B-half h at 32768 + h*16384. Row r: LDS chunk c = global chunk c^(r&7).
// Stage ledger: ph0:A0(t+1) ph1:A1(t+1) ph2:B0(t+2) ph3:B1(t+2)+vmcnt(4)
// (leaves exactly B(t+2) in flight; proves A(t+1),B(t+1) landed).
// ---------------------------------------------------------------------------
__device__ __forceinline__ void mfma_loop256(
    const char* Ab, const char* Bb, size_t ldaB, size_t ldbB, int K,
    char* lds, f32x4 acc[8][4])
{
  const int tid = threadIdx.x;
  const int w = tid >> 6, l = tid & 63;
  const int wm = w >> 2, wn = w & 3;
  const int m16 = l & 15, q = l >> 4;
  const int swz = m16 & 7;
  const int aBase = wm * 16384 + m16 * 128;
  const int bBase = 32768 + (wn >> 1) * 16384 + ((wn & 1) * 64 + m16) * 128;
  const int srcCh = ((l & 7) ^ ((l >> 3) & 7)) << 4;
  const size_t gA0 = (size_t)(w * 16 + (l >> 3)) * ldaB + srcCh;
  const size_t gB0 = (size_t)(w * 16 + (l >> 3)) * ldbB + srcCh;
  const int dstW = w * 2048;
  const int NT = K >> 6;

  bf16x8 af[4][2], bv[4][2];

#define STG_A(h, tau)                                                          \
  {                                                                            \
    char* d = lds + (((tau) & 1) * 65536) + (h) * 16384 + dstW;                \
    const char* g = Ab + gA0 + (size_t)((h) * 128) * ldaB + (size_t)(tau) * 128;\
    GLL16(g, d);                                                               \
    GLL16(g + 8 * ldaB, d + 1024);                                             \
  }
#define STG_B(h, tau)                                                          \
  {                                                                            \
    char* d = lds + (((tau) & 1) * 65536) + 32768 + (h) * 16384 + dstW;        \
    const char* g = Bb + gB0 + (size_t)((h) * 128) * ldbB + (size_t)(tau) * 128;\
    GLL16(g, d);                                                               \
    GLL16(g + 8 * ldbB, d + 1024);                                             \
  }
#define RD_A(lo, p)                                                            \
  _Pragma("unroll") for (int mi = 0; mi < 4; ++mi)                             \
  _Pragma("unroll") for (int ks = 0; ks < 2; ++ks)                             \
    af[mi][ks] = *(const bf16x8*)(lds + (p) * 65536 + aBase +                  \
        ((lo) * 4 + mi) * 2048 + (((ks * 4 + q) ^ swz) << 4));
#define RD_B(no, p)                                                            \
  _Pragma("unroll") for (int nj = 0; nj < 2; ++nj)                             \
  _Pragma("unroll") for (int ks = 0; ks < 2; ++ks)                             \
    bv[(no) * 2 + nj][ks] = *(const bf16x8*)(lds + (p) * 65536 + bBase +       \
        ((no) * 2 + nj) * 2048 + (((ks * 4 + q) ^ swz) << 4));
#define MM(lo, no)                                                             \
  __builtin_amdgcn_s_setprio(1);                                               \
  _Pragma("unroll") for (int mi = 0; mi < 4; ++mi)                             \
  _Pragma("unroll") for (int nj = 0; nj < 2; ++nj)                             \
  _Pragma("unroll") for (int ks = 0; ks < 2; ++ks)                             \
    acc[(lo) * 4 + mi][(no) * 2 + nj] =                                        \
        __builtin_amdgcn_mfma_f32_16x16x32_bf16(                               \
            af[mi][ks], bv[(no) * 2 + nj][ks],                                 \
            acc[(lo) * 4 + mi][(no) * 2 + nj], 0, 0, 0);                       \
  __builtin_amdgcn_s_setprio(0);
#define SB __builtin_amdgcn_sched_barrier(0)
#define BAR { SB; __builtin_amdgcn_s_barrier(); SB; }
#define VMW(n) asm volatile("s_waitcnt vmcnt(" #n ")" ::: "memory")

  // Prologue: tile 0 (all 4 halves) + B halves of tile 1. vmcnt(4) leaves
  // B(1) outstanding, tile 0 landed.
  STG_A(0, 0); STG_A(1, 0); STG_B(0, 0); STG_B(1, 0);
  STG_B(0, 1); STG_B(1, 1);
  VMW(4);
  BAR;

  int t = 0;
  for (; t < NT - 2; ++t) {
    const int p = t & 1;
    RD_A(0, p); RD_B(0, p);
    STG_A(0, t + 1);
    BAR; MM(0, 0); BAR;
    RD_B(1, p);
    STG_A(1, t + 1);
    BAR; MM(0, 1); BAR;
    RD_A(1, p);
    STG_B(0, t + 2);
    BAR; MM(1, 0); BAR;
    STG_B(1, t + 2);
    BAR; MM(1, 1); SB; VMW(4); BAR;
  }
  {  // t = NT-2: stage only A(NT-1); drain fully at ph3
    const int p = t & 1;
    RD_A(0, p); RD_B(0, p);
    STG_A(0, t + 1);
    BAR; MM(0, 0); BAR;
    RD_B(1, p);
    STG_A(1, t + 1);
    BAR; MM(0, 1); BAR;
    RD_A(1, p);
    BAR; MM(1, 0); BAR;
    BAR; MM(1, 1); SB; VMW(0); BAR;
    ++t;
  }
  {  // t = NT-1: all resident, no stages -> no barriers
    const int p = t & 1;
    RD_A(0, p); RD_B(0, p);
    MM(0, 0);
    RD_B(1, p);
    MM(0, 1);
    RD_A(1, p);
    MM(1, 0);
    MM(1, 1);
  }
#undef STG_A
#undef STG_B
#undef RD_A
#undef RD_B
#undef MM
#undef SB
#undef BAR
#undef VMW
}

// bijective XCD-chunked block swizzle (nwg % 8 == 0 for all our grids)
__device__ __forceinline__ int xcd_swz(int id, int nwg) {
  return ((nwg & 7) == 0) ? ((id & 7) * (nwg >> 3) + (id >> 3)) : id;
}

// ---------------------------------------------------------------------------
// GEMM1: Hs[t, zcol+h] = P[t,e] * gelu(Xb @ W1T_e^T + b1_e)   (bf16 store)
// grid (8, N/256, Z), 512 threads
// ---------------------------------------------------------------------------
__global__ __launch_bounds__(512, 2) void gemm1_kernel(
    const __bf16* __restrict__ X, const __bf16* __restrict__ W1T,
    const float* __restrict__ b1, const float* __restrict__ P,
    __bf16* __restrict__ Hs, int hs_ld, int e_off, size_t b_zstride)
{
  __shared__ __align__(16) char lds[131072];
  const int nwg = gridDim.x * gridDim.y * gridDim.z;
  const int id = blockIdx.x + gridDim.x * (blockIdx.y + gridDim.y * blockIdx.z);
  const int wg = xcd_swz(id, nwg);
  const int bm = wg & 7;
  const int bn = (wg >> 3) % gridDim.y;
  const int z = wg / (gridDim.y << 3);
  const int e = z + e_off;

  f32x4 acc[8][4];
  const f32x4 z4 = {0.f, 0.f, 0.f, 0.f};
#pragma unroll
  for (int i = 0; i < 8; ++i)
#pragma unroll
    for (int j = 0; j < 4; ++j) acc[i][j] = z4;

  const char* A = (const char*)(X + (size_t)bm * 256 * 1024);
  const char* B = (const char*)(W1T + (size_t)z * b_zstride +
                                (size_t)bn * 256 * 1024);
  mfma_loop256(A, B, 2048, 2048, 1024, lds, acc);

  const int tid = threadIdx.x, w = tid >> 6, l = tid & 63;
  const int wm = w >> 2, wn = w & 3, q = l >> 4, m16 = l & 15;
  const int row0 = bm * 256 + wm * 128 + q * 4;
  const int colE = bn * 256 + wn * 64 + m16;
  const int zcol = (hs_ld == 4096) ? 0 : z * 4096;
  float b1v[4];
#pragma unroll
  for (int nj = 0; nj < 4; ++nj)
    b1v[nj] = b1[(size_t)e * 4096 + colE + nj * 16];
#pragma unroll
  for (int mi = 0; mi < 8; ++mi) {
    float pv[4];
#pragma unroll
    for (int r = 0; r < 4; ++r)
      pv[r] = P[(size_t)(row0 + mi * 16 + r) * 8 + e];
#pragma unroll
    for (int nj = 0; nj < 4; ++nj)
#pragma unroll
      for (int r = 0; r < 4; ++r) {
        float h = acc[mi][nj][r] + b1v[nj];
        float o = gelu_f(h) * pv[r];
        Hs[(size_t)(row0 + mi * 16 + r) * hs_ld + zcol + colE + nj * 16] =
            (__bf16)o;
      }
  }
}

// ---------------------------------------------------------------------------
// GEMM2: y[t,d] += Hs_chunk @ W2T_chunk^T (split-K via z, fp32 atomics into
// the bias-pre-initialized output). grid (8, 4, Z), 512 threads.
// ---------------------------------------------------------------------------
__global__ __launch_bounds__(512, 2) void gemm2_kernel(
    const __bf16* __restrict__ Hs, const __bf16* __restrict__ W2T,
    float* __restrict__ y, int lda, int ldb, int kz, int Kb)
{
  __shared__ __align__(16) char lds[131072];
  const int nwg = gridDim.x * gridDim.y * gridDim.z;
  const int id = blockIdx.x + gridDim.x * (blockIdx.y + gridDim.y * blockIdx.z);
  const int wg = xcd_swz(id, nwg);
  const int bm = wg & 7;
  const int bn = (wg >> 3) % gridDim.y;
  const int z = wg / (gridDim.y << 3);

  f32x4 acc[8][4];
  const f32x4 z4 = {0.f, 0.f, 0.f, 0.f};
#pragma unroll
  for (int i = 0; i < 8; ++i)
#pragma unroll
    for (int j = 0; j < 4; ++j) acc[i][j] = z4;

  const char* A = (const char*)(Hs + (size_t)bm * 256 * lda + (size_t)z * kz);
  const char* B = (const char*)(W2T + (size_t)bn * 256 * ldb + (size_t)z * kz);
  mfma_loop256(A, B, (size_t)lda * 2, (size_t)ldb * 2, Kb, lds, acc);

  const int tid = threadIdx.x, w = tid >> 6, l = tid & 63;
  const int wm = w >> 2, wn = w & 3, q = l >> 4, m16 = l & 15;
  const int row0 = bm * 256 + wm * 128 + q * 4;
  const int col0 = bn * 256 + wn * 64 + m16;
#pragma unroll
  for (int mi = 0; mi < 8; ++mi)
#pragma unroll
    for (int nj = 0; nj < 4; ++nj)
#pragma unroll
      for (int r = 0; r < 4; ++r)
        unsafeAtomicAdd(
            y + (size_t)(row0 + mi * 16 + r) * 1024 + col0 + nj * 16,
            acc[mi][nj][r]);
}

// ---------------------------------------------------------------------------
// Tier D: zero-workspace fused VALU fallback (fp32)
// ---------------------------------------------------------------------------
__global__ __launch_bounds__(256) void fused_naive_kernel(
    const float* __restrict__ x, const float* __restrict__ w1,
    const float* __restrict__ b1, const float* __restrict__ w2,
    const float* __restrict__ b2, const float* __restrict__ probs,
    float* __restrict__ y)
{
  __shared__ float xs[8][1024];
  __shared__ float gs[8][64];
  __shared__ float ps[8];
  const int tid = threadIdx.x;
  const int t0 = blockIdx.x * 8;
  const size_t DH = (size_t)1024 * 4096;
  const int tt = tid >> 5;
  const int d0 = (tid & 31) * 32;
  float acc[32];
#pragma unroll
  for (int i = 0; i < 32; ++i) acc[i] = 0.f;
  {
    const f32x4* xsrc = (const f32x4*)(x + (size_t)t0 * 1024);
    f32x4* xdst = (f32x4*)&xs[0][0];
    for (int i = tid; i < 2048; i += 256) xdst[i] = xsrc[i];
  }
  const int wv = tid >> 6;
  const int hl = tid & 63;
  for (int e = 0; e < 8; ++e) {
    if (tid < 8) ps[tid] = probs[(size_t)(t0 + tid) * 8 + e];
    __syncthreads();
    for (int hc = 0; hc < 4096; hc += 64) {
      float a0 = 0.f, a1 = 0.f;
      const float* w1p = w1 + (size_t)e * DH + hc + hl;
      for (int d = 0; d < 1024; ++d) {
        float wvv = w1p[(size_t)d * 4096];
        a0 += xs[wv * 2 + 0][d] * wvv;
        a1 += xs[wv * 2 + 1][d] * wvv;
      }
      __syncthreads();
      gs[wv * 2 + 0][hl] =
          ps[wv * 2 + 0] * gelu_f(a0 + b1[(size_t)e * 4096 + hc + hl]);
      gs[wv * 2 + 1][hl] =
          ps[wv * 2 + 1] * gelu_f(a1 + b1[(size_t)e * 4096 + hc + hl]);
      __syncthreads();
      const float* w2p = w2 + (size_t)e * DH + (size_t)hc * 1024 + d0;
      for (int hh = 0; hh < 64; ++hh) {
        float g = gs[tt][hh];
#pragma unroll
        for (int jb = 0; jb < 8; ++jb) {
          f32x4 w4 = *(const f32x4*)(w2p + (size_t)hh * 1024 + jb * 4);
#pragma unroll
          for (int j2 = 0; j2 < 4; ++j2) acc[jb * 4 + j2] += g * w4[j2];
        }
      }
    }
#pragma unroll
    for (int j = 0; j < 32; ++j)
      acc[j] += ps[tt] * b2[(size_t)e * 1024 + d0 + j];
    __syncthreads();
  }
  float* yp = y + (size_t)(t0 + tt) * 1024 + d0;
#pragma unroll
  for (int jb = 0; jb < 8; ++jb) {
    f32x4 o = {acc[jb * 4], acc[jb * 4 + 1], acc[jb * 4 + 2], acc[jb * 4 + 3]};
    *(f32x4*)(yp + jb * 4) = o;
  }
}

// ---------------------------------------------------------------------------
extern "C" void kernel_launch(void* const* d_in, const int* in_sizes, int n_in,
                              void* d_out, int out_size, void* d_ws,
                              size_t ws_size, hipStream_t stream)
{
  const float* x  = (const float*)d_in[0];  // [2048,1024]
  const float* rw = (const float*)d_in[1];  // [1024,8]
  const float* rb = (const float*)d_in[2];  // [8]
  const float* w1 = (const float*)d_in[3];  // [8,1024,4096]
  const float* b1 = (const float*)d_in[4];  // [8,4096]
  const float* w2 = (const float*)d_in[5];  // [8,4096,1024]
  const float* b2 = (const float*)d_in[6];  // [8,1024]
  float* y = (float*)d_out;                   // [2048,1024]
  float* probs_out = y + (size_t)2048 * 1024; // [2048,8]

  const size_t DH = (size_t)1024 * 4096;
  const size_t BASE = (64 << 10) + (size_t)2048 * 1024 * 2;      // P | xb
  const size_t TA = BASE + 8 * DH * 2 + (size_t)2048 * 32768 * 2;  // ~196.1MB
  const size_t TB = BASE + DH * 2 + (size_t)2048 * 4096 * 2;       // ~28.1MB

  char* ws = (char*)d_ws;
  float* P = (float*)ws;
  __bf16* xb = (__bf16*)(ws + (64 << 10));
  __bf16* WT = (__bf16*)(ws + BASE);

  if (ws_size >= TA) {
    pre_kernel<<<512, 256, 0, stream>>>(x, rw, rb, b2, P, probs_out, xb, y);
    __bf16* Hs = WT + 8 * DH;       // [2048][32768] bf16
    transconv_kernel<<<dim3(16, 64, 8), 256, 0, stream>>>(
        w1, WT, 1024, 4096, 1024, DH);
    gemm1_kernel<<<dim3(8, 16, 8), 512, 0, stream>>>(xb, WT, b1, P, Hs,
                                                     32768, 0, DH);
    transconv_kernel<<<dim3(64, 16, 8), 256, 0, stream>>>(
        w2, WT, 4096, 1024, 32768, 4096);
    gemm2_kernel<<<dim3(8, 4, 8), 512, 0, stream>>>(Hs, WT, y, 32768,
                                                    32768, 4096, 4096);
  } else if (ws_size >= TB) {
    pre_kernel<<<512, 256, 0, stream>>>(x, rw, rb, b2, P, probs_out, xb, y);
    __bf16* HsE = WT + DH;          // 16 MB
    for (int e = 0; e < 8; ++e) {
      transconv_kernel<<<dim3(16, 64, 1), 256, 0, stream>>>(
          w1 + (size_t)e * DH, WT, 1024, 4096, 1024, 0);
      gemm1_kernel<<<dim3(8, 16, 1), 512, 0, stream>>>(xb, WT, b1, P, HsE,
                                                       4096, e, 0);
      transconv_kernel<<<dim3(64, 16, 1), 256, 0, stream>>>(
          w2 + (size_t)e * DH, WT, 4096, 1024, 4096, 0);
      gemm2_kernel<<<dim3(8, 4, 4), 512, 0, stream>>>(HsE, WT, y, 4096,
                                                      4096, 1024, 1024);
    }
  } else {
    router_kernel<<<512, 256, 0, stream>>>(x, rw, rb, probs_out);
    fused_naive_kernel<<<256, 256, 0, stream>>>(x, w1, b1, w2, b2, probs_out,
                                                y);
  }
}

// Round 6
// 607.564 us; speedup vs baseline: 1.5187x; 1.0030x over previous
//
#include <hip/hip_runtime.h>
#include <math.h>

// ============================================================================
// MoE FFN (dense, E=8): y = sum_e softmax(x@Wr)[:,e] * (gelu(x@W1_e+b1_e)@W2_e+b2_e)
// T=2048, D=1024, H=4096, E=8. FP32 in/out; bf16 MFMA compute.
// R9 -> R10: transconv rewritten for latency (it was ~130us each, ~1.5TB/s):
// 64x256 tiles, 16 indep f32x4 loads/thread (4x MLP), cvt->bf16 BEFORE LDS
// (tile 33KB -> 4 blocks/CU), 1 barrier, 2-way-free banks both sides,
// fully-coalesced 256B read beats + 128B column stores. pre_kernel now also
// writes P^T[8][2048]; gemm1 reads probs via wave-broadcast PT loads (P buf
// dropped). GEMM cores identical to R9 (verified: 165us, MfmaUtil 36%, 0
// bank conflicts): 4-phase BK=64 dbuf, GLL16 both operands, chunk^(row&7),
// vmcnt(4) counted waits, setprio, XCD swizzle.
// ws: PT | xb | WT | Hs. Tiers: A >=196.2MB, B >=28.2MB, D zero-ws fallback.
// ============================================================================

typedef float f32x4 __attribute__((ext_vector_type(4)));
typedef __bf16 bf16x8 __attribute__((ext_vector_type(8)));

#define GLL16(gp, lp)                                                          \
  __builtin_amdgcn_global_load_lds(                                            \
      (const __attribute__((address_space(1))) void*)(gp),                     \
      (__attribute__((address_space(3))) void*)(lp), 16, 0, 0)

// Branch-free GELU: erf via Abramowitz-Stegun 7.1.26 (|err| <= 1.5e-7).
__device__ __forceinline__ float gelu_f(float h) {
  float x = h * 0.70710678118654752f;
  float ax = fabsf(x);
  float t = __builtin_amdgcn_rcpf(fmaf(0.3275911f, ax, 1.0f));
  float p = fmaf(1.061405429f, t, -1.453152027f);
  p = fmaf(p, t, 1.421413741f);
  p = fmaf(p, t, -0.284496736f);
  p = fmaf(p, t, 0.254829592f);
  float e = __expf(-x * x);
  float erfv = fmaf(-p * t, e, 1.0f);
  erfv = copysignf(erfv, x);
  return 0.5f * h * (1.0f + erfv);
}

// ---------------------------------------------------------------------------
// pre_kernel: per row t -- router softmax (PT + probs_out), x -> bf16 (xb),
// y bias-init y[t] = sum_e P[t,e]*b2[e].  grid 512 x 256 (4 rows/block,
// 64 lanes/row; lane l owns d = l*16..l*16+15).
// ---------------------------------------------------------------------------
__global__ void pre_kernel(const float* __restrict__ x,
                           const float* __restrict__ rw,
                           const float* __restrict__ rb,
                           const float* __restrict__ b2,
                           float* __restrict__ PT,        // [8][2048]
                           float* __restrict__ probs_out,
                           __bf16* __restrict__ xb,
                           float* __restrict__ y)
{
  __shared__ float ps[4][8];
  const int tid = threadIdx.x;
  const int g = tid >> 6, l = tid & 63;
  const int t = blockIdx.x * 4 + g;
  const int d0 = l * 16;
  const float* xr = x + (size_t)t * 1024 + d0;

  f32x4 xv[4];
#pragma unroll
  for (int i = 0; i < 4; ++i) xv[i] = *(const f32x4*)(xr + i * 4);

  // cvt store (bf16x8 x2)
  {
    bf16x8 o0, o1;
#pragma unroll
    for (int j = 0; j < 8; ++j) {
      o0[j] = (__bf16)xv[j >> 2][j & 3];
      o1[j] = (__bf16)xv[2 + (j >> 2)][j & 3];
    }
    *(bf16x8*)(xb + (size_t)t * 1024 + d0) = o0;
    *(bf16x8*)(xb + (size_t)t * 1024 + d0 + 8) = o1;
  }

  // router partial dot over this lane's 16 d
  float a[8];
#pragma unroll
  for (int e = 0; e < 8; ++e) a[e] = 0.f;
#pragma unroll
  for (int i = 0; i < 16; ++i) {
    float xs = xv[i >> 2][i & 3];
    const float* wr = rw + (size_t)(d0 + i) * 8;
    f32x4 w0 = *(const f32x4*)(wr);
    f32x4 w1 = *(const f32x4*)(wr + 4);
#pragma unroll
    for (int e = 0; e < 4; ++e) a[e] = fmaf(xs, w0[e], a[e]);
#pragma unroll
    for (int e = 0; e < 4; ++e) a[4 + e] = fmaf(xs, w1[e], a[4 + e]);
  }
#pragma unroll
  for (int off = 32; off > 0; off >>= 1) {
#pragma unroll
    for (int e = 0; e < 8; ++e) a[e] += __shfl_down(a[e], off);
  }
  if (l == 0) {
#pragma unroll
    for (int e = 0; e < 8; ++e) a[e] += rb[e];
    float m = a[0];
#pragma unroll
    for (int e = 1; e < 8; ++e) m = fmaxf(m, a[e]);
    float s = 0.f;
#pragma unroll
    for (int e = 0; e < 8; ++e) { a[e] = __expf(a[e] - m); s += a[e]; }
    float inv = 1.f / s;
#pragma unroll
    for (int e = 0; e < 8; ++e) {
      float p = a[e] * inv;
      PT[(size_t)e * 2048 + t] = p;
      probs_out[t * 8 + e] = p;
      ps[g][e] = p;
    }
  }
  __syncthreads();

  // y bias-init: y[t][d] = sum_e p[e]*b2[e][d]
  f32x4 acc[4];
#pragma unroll
  for (int i = 0; i < 4; ++i) acc[i] = {0.f, 0.f, 0.f, 0.f};
#pragma unroll
  for (int e = 0; e < 8; ++e) {
    float p = ps[g][e];
#pragma unroll
    for (int i = 0; i < 4; ++i) {
      f32x4 b = *(const f32x4*)(b2 + (size_t)e * 1024 + d0 + i * 4);
#pragma unroll
      for (int c = 0; c < 4; ++c) acc[i][c] = fmaf(p, b[c], acc[i][c]);
    }
  }
#pragma unroll
  for (int i = 0; i < 4; ++i)
    *(f32x4*)(y + (size_t)t * 1024 + d0 + i * 4) = acc[i];
}

// ---------------------------------------------------------------------------
// Router only (tier D): logits = x @ rw + rb, softmax -> probs_out
// ---------------------------------------------------------------------------
__global__ void router_kernel(const float* __restrict__ x,
                              const float* __restrict__ rw,
                              const float* __restrict__ rb,
                              float* __restrict__ probs_out)
{
  int gid = blockIdx.x * blockDim.x + threadIdx.x;
  int t = gid >> 6;
  int l = gid & 63;
  const float* xr = x + (size_t)t * 1024;
  float a[8];
#pragma unroll
  for (int e = 0; e < 8; ++e) a[e] = 0.f;
  for (int d = l; d < 1024; d += 64) {
    float xv = xr[d];
    f32x4 w0 = *(const f32x4*)(rw + d * 8);
    f32x4 w1 = *(const f32x4*)(rw + d * 8 + 4);
#pragma unroll
    for (int e = 0; e < 4; ++e) a[e] += xv * w0[e];
#pragma unroll
    for (int e = 0; e < 4; ++e) a[4 + e] += xv * w1[e];
  }
#pragma unroll
  for (int off = 32; off > 0; off >>= 1) {
#pragma unroll
    for (int e = 0; e < 8; ++e) a[e] += __shfl_down(a[e], off);
  }
  if (l == 0) {
#pragma unroll
    for (int e = 0; e < 8; ++e) a[e] += rb[e];
    float m = a[0];
#pragma unroll
    for (int e = 1; e < 8; ++e) m = fmaxf(m, a[e]);
    float s = 0.f;
#pragma unroll
    for (int e = 0; e < 8; ++e) { a[e] = __expf(a[e] - m); s += a[e]; }
    float inv = 1.f / s;
#pragma unroll
    for (int e = 0; e < 8; ++e) probs_out[t * 8 + e] = a[e] * inv;
  }
}

// ---------------------------------------------------------------------------
// Transpose+convert: src fp32 [z][R][C] -> dst bf16 [c][dstLd] (+ z*zOff
// element offset) holding src[r][c] at [c][.. + r].
// 64 rows x 256 cols per block, 256 threads, grid (R/64, C/256, Z).
// Reads: 16 indep f32x4/thread, each 16-lane beat = 256B contiguous row
// segment. Convert fp32->bf16 BEFORE LDS (tile 33KB -> 4 blocks/CU).
// LDS [64][257] bf16: write beats stride-8B (1 lane/bank); read gather
// bank = (4a + (b>>1) + k) % 32 -> 2 lanes/bank (free). One barrier.
// Stores: 8 lanes x 16B = 128B contiguous per column, 8 cols/wave/instr.
// ---------------------------------------------------------------------------
__global__ void transconv_kernel(const float* __restrict__ src,
                                 __bf16* __restrict__ dst,
                                 int R, int C, size_t dstLd, size_t zOff)
{
  __shared__ __bf16 tile[64][257];
  size_t bs = (size_t)blockIdx.z * (size_t)R * (size_t)C;
  size_t dzo = (size_t)blockIdx.z * zOff;
  int r0 = blockIdx.x * 64, c0 = blockIdx.y * 256;
  const int l15 = (threadIdx.x & 15) * 4;
  const int rq = threadIdx.x >> 4;          // 0..15
#pragma unroll
  for (int i = 0; i < 4; ++i) {
    const int row = rq + 16 * i;
    const float* sr = src + bs + (size_t)(r0 + row) * C + c0 + l15;
#pragma unroll
    for (int q = 0; q < 4; ++q) {
      f32x4 v = *(const f32x4*)(sr + q * 64);
#pragma unroll
      for (int j = 0; j < 4; ++j)
        tile[row][q * 64 + l15 + j] = (__bf16)v[j];
    }
  }
  __syncthreads();
  const int cb = threadIdx.x >> 3;          // 0..31
  const int orr = (threadIdx.x & 7) * 8;
#pragma unroll
  for (int g = 0; g < 8; ++g) {
    const int c = cb + 32 * g;
    bf16x8 o;
#pragma unroll
    for (int j = 0; j < 8; ++j) o[j] = tile[orr + j][c];
    *(bf16x8*)(dst + (size_t)(c0 + c) * dstLd + dzo + r0 + orr) = o;
  }
}

// ---------------------------------------------------------------------------
// 4-phase 256x256 MFMA mainloop, BK=64 (verified structure, unchanged).
// 8 waves (wm=w>>2, wn=w&3), per-wave out 128x64 = 8x4 frags of 16x16x32,
// 64 MFMA / K-tile / wave in 4 quadrant phases of 16.
// LDS: buf p (p=t&1) at p*65536: A-half h (128 rows x 128B) at h*16384,
// B-half h at 32768 + h*16384. Row r: LDS chunk c = global chunk c^(r&7).
// Stage ledger: ph0:A0(t+1) ph1:A1(t+1) ph2:B0(t+2) ph3:B1(t+2)+vmcnt(4)
// (leaves exactly B(t+2) in flight; proves A(t+1),B(t+1) landed).
// ---------------------------------------------------------------------------
__device__ __forceinline__ void mfma_loop256(
    const char* Ab, const char* Bb, size_t ldaB, size_t ldbB, int K,
    char* lds, f32x4 acc[8][4])
{
  const int tid = threadIdx.x;
  const int w = tid >> 6, l = tid & 63;
  const int wm = w >> 2, wn = w & 3;
  const int m16 = l & 15, q = l >> 4;
  const int swz = m16 & 7;
  const int aBase = wm * 16384 + m16 * 128;
  const int bBase = 32768 + (wn >> 1) * 16384 + ((wn & 1) * 64 + m16) * 128;
  const int srcCh = ((l & 7) ^ ((l >> 3) & 7)) << 4;
  const size_t gA0 = (size_t)(w * 16 + (l >> 3)) * ldaB + srcCh;
  const size_t gB0 = (size_t)(w * 16 + (l >> 3)) * ldbB + srcCh;
  const int dstW = w * 2048;
  const int NT = K >> 6;

  bf16x8 af[4][2], bv[4][2];

#define STG_A(h, tau)                                                          \
  {                                                                            \
    char* d = lds + (((tau) & 1) * 65536) + (h) * 16384 + dstW;                \
    const char* g = Ab + gA0 + (size_t)((h) * 128) * ldaB + (size_t)(tau) * 128;\
    GLL16(g, d);                                                               \
    GLL16(g + 8 * ldaB, d + 1024);                                             \
  }
#define STG_B(h, tau)                                                          \
  {                                                                            \
    char* d = lds + (((tau) & 1) * 65536) + 32768 + (h) * 16384 + dstW;        \
    const char* g = Bb + gB0 + (size_t)((h) * 128) * ldbB + (size_t)(tau) * 128;\
    GLL16(g, d);                                                               \
    GLL16(g + 8 * ldbB, d + 1024);                                             \
  }
#define RD_A(lo, p)                                                            \
  _Pragma("unroll") for (int mi = 0; mi < 4; ++mi)                             \
  _Pragma("unroll") for (int ks = 0; ks < 2; ++ks)                             \
    af[mi][ks] = *(const bf16x8*)(lds + (p) * 65536 + aBase +                  \
        ((lo) * 4 + mi) * 2048 + (((ks * 4 + q) ^ swz) << 4));
#define RD_B(no, p)                                                            \
  _Pragma("unroll") for (int nj = 0; nj < 2; ++nj)                             \
  _Pragma("unroll") for (int ks = 0; ks < 2; ++ks)                             \
    bv[(no) * 2 + nj][ks] = *(const bf16x8*)(lds + (p) * 65536 + bBase +       \
        ((no) * 2 + nj) * 2048 + (((ks * 4 + q) ^ swz) << 4));
#define MM(lo, no)                                                             \
  __builtin_amdgcn_s_setprio(1);                                               \
  _Pragma("unroll") for (int mi = 0; mi < 4; ++mi)                             \
  _Pragma("unroll") for (int nj = 0; nj < 2; ++nj)                             \
  _Pragma("unroll") for (int ks = 0; ks < 2; ++ks)                             \
    acc[(lo) * 4 + mi][(no) * 2 + nj] =                                        \
        __builtin_amdgcn_mfma_f32_16x16x32_bf16(                               \
            af[mi][ks], bv[(no) * 2 + nj][ks],                                 \
            acc[(lo) * 4 + mi][(no) * 2 + nj], 0, 0, 0);                       \
  __builtin_amdgcn_s_setprio(0);
#define SB __builtin_amdgcn_sched_barrier(0)
#define BAR { SB; __builtin_amdgcn_s_barrier(); SB; }
#define VMW(n) asm volatile("s_waitcnt vmcnt(" #n ")" ::: "memory")

  // Prologue: tile 0 (all 4 halves) + B halves of tile 1. vmcnt(4) leaves
  // B(1) outstanding, tile 0 landed.
  STG_A(0, 0); STG_A(1, 0); STG_B(0, 0); STG_B(1, 0);
  STG_B(0, 1); STG_B(1, 1);
  VMW(4);
  BAR;

  int t = 0;
  for (; t < NT - 2; ++t) {
    const int p = t & 1;
    RD_A(0, p); RD_B(0, p);
    STG_A(0, t + 1);
    BAR; MM(0, 0); BAR;
    RD_B(1, p);
    STG_A(1, t + 1);
    BAR; MM(0, 1); BAR;
    RD_A(1, p);
    STG_B(0, t + 2);
    BAR; MM(1, 0); BAR;
    STG_B(1, t + 2);
    BAR; MM(1, 1); SB; VMW(4); BAR;
  }
  {  // t = NT-2: stage only A(NT-1); drain fully at ph3
    const int p = t & 1;
    RD_A(0, p); RD_B(0, p);
    STG_A(0, t + 1);
    BAR; MM(0, 0); BAR;
    RD_B(1, p);
    STG_A(1, t + 1);
    BAR; MM(0, 1); BAR;
    RD_A(1, p);
    BAR; MM(1, 0); BAR;
    BAR; MM(1, 1); SB; VMW(0); BAR;
    ++t;
  }
  {  // t = NT-1: all resident, no stages -> no barriers
    const int p = t & 1;
    RD_A(0, p); RD_B(0, p);
    MM(0, 0);
    RD_B(1, p);
    MM(0, 1);
    RD_A(1, p);
    MM(1, 0);
    MM(1, 1);
  }
#undef STG_A
#undef STG_B
#undef RD_A
#undef RD_B
#undef MM
#undef SB
#undef BAR
#undef VMW
}

// bijective XCD-chunked block swizzle (nwg % 8 == 0 for all our grids)
__device__ __forceinline__ int xcd_swz(int id, int nwg) {
  return ((nwg & 7) == 0) ? ((id & 7) * (nwg >> 3) + (id >> 3)) : id;
}

// ---------------------------------------------------------------------------
// GEMM1: Hs[t, zcol+h] = PT[e,t] * gelu(Xb @ W1T_e^T + b1_e)   (bf16 store)
// grid (8, N/256, Z), 512 threads
// ---------------------------------------------------------------------------
__global__ __launch_bounds__(512, 2) void gemm1_kernel(
    const __bf16* __restrict__ X, const __bf16* __restrict__ W1T,
    const float* __restrict__ b1, const float* __restrict__ PT,
    __bf16* __restrict__ Hs, int hs_ld, int e_off, size_t b_zstride)
{
  __shared__ __align__(16) char lds[131072];
  const int nwg = gridDim.x * gridDim.y * gridDim.z;
  const int id = blockIdx.x + gridDim.x * (blockIdx.y + gridDim.y * blockIdx.z);
  const int wg = xcd_swz(id, nwg);
  const int bm = wg & 7;
  const int bn = (wg >> 3) % gridDim.y;
  const int z = wg / (gridDim.y << 3);
  const int e = z + e_off;

  f32x4 acc[8][4];
  const f32x4 z4 = {0.f, 0.f, 0.f, 0.f};
#pragma unroll
  for (int i = 0; i < 8; ++i)
#pragma unroll
    for (int j = 0; j < 4; ++j) acc[i][j] = z4;

  const char* A = (const char*)(X + (size_t)bm * 256 * 1024);
  const char* B = (const char*)(W1T + (size_t)z * b_zstride +
                                (size_t)bn * 256 * 1024);
  mfma_loop256(A, B, 2048, 2048, 1024, lds, acc);

  const int tid = threadIdx.x, w = tid >> 6, l = tid & 63;
  const int wm = w >> 2, wn = w & 3, q = l >> 4, m16 = l & 15;
  const int row0 = bm * 256 + wm * 128 + q * 4;
  const int colE = bn * 256 + wn * 64 + m16;
  const int zcol = (hs_ld == 4096) ? 0 : z * 4096;
  float b1v[4];
#pragma unroll
  for (int nj = 0; nj < 4; ++nj)
    b1v[nj] = b1[(size_t)e * 4096 + colE + nj * 16];
#pragma unroll
  for (int mi = 0; mi < 8; ++mi) {
    float pv[4];
#pragma unroll
    for (int r = 0; r < 4; ++r)
      pv[r] = PT[(size_t)e * 2048 + row0 + mi * 16 + r];
#pragma unroll
    for (int nj = 0; nj < 4; ++nj)
#pragma unroll
      for (int r = 0; r < 4; ++r) {
        float h = acc[mi][nj][r] + b1v[nj];
        float o = gelu_f(h) * pv[r];
        Hs[(size_t)(row0 + mi * 16 + r) * hs_ld + zcol + colE + nj * 16] =
            (__bf16)o;
      }
  }
}

// ---------------------------------------------------------------------------
// GEMM2: y[t,d] += Hs_chunk @ W2T_chunk^T (split-K via z, fp32 atomics into
// the bias-pre-initialized output). grid (8, 4, Z), 512 threads.
// ---------------------------------------------------------------------------
__global__ __launch_bounds__(512, 2) void gemm2_kernel(
    const __bf16* __restrict__ Hs, const __bf16* __restrict__ W2T,
    float* __restrict__ y, int lda, int ldb, int kz, int Kb)
{
  __shared__ __align__(16) char lds[131072];
  const int nwg = gridDim.x * gridDim.y * gridDim.z;
  const int id = blockIdx.x + gridDim.x * (blockIdx.y + gridDim.y * blockIdx.z);
  const int wg = xcd_swz(id, nwg);
  const int bm = wg & 7;
  const int bn = (wg >> 3) % gridDim.y;
  const int z = wg / (gridDim.y << 3);

  f32x4 acc[8][4];
  const f32x4 z4 = {0.f, 0.f, 0.f, 0.f};
#pragma unroll
  for (int i = 0; i < 8; ++i)
#pragma unroll
    for (int j = 0; j < 4; ++j) acc[i][j] = z4;

  const char* A = (const char*)(Hs + (size_t)bm * 256 * lda + (size_t)z * kz);
  const char* B = (const char*)(W2T + (size_t)bn * 256 * ldb + (size_t)z * kz);
  mfma_loop256(A, B, (size_t)lda * 2, (size_t)ldb * 2, Kb, lds, acc);

  const int tid = threadIdx.x, w = tid >> 6, l = tid & 63;
  const int wm = w >> 2, wn = w & 3, q = l >> 4, m16 = l & 15;
  const int row0 = bm * 256 + wm * 128 + q * 4;
  const int col0 = bn * 256 + wn * 64 + m16;
#pragma unroll
  for (int mi = 0; mi < 8; ++mi)
#pragma unroll
    for (int nj = 0; nj < 4; ++nj)
#pragma unroll
      for (int r = 0; r < 4; ++r)
        unsafeAtomicAdd(
            y + (size_t)(row0 + mi * 16 + r) * 1024 + col0 + nj * 16,
            acc[mi][nj][r]);
}

// ---------------------------------------------------------------------------
// Tier D: zero-workspace fused VALU fallback (fp32)
// ---------------------------------------------------------------------------
__global__ __launch_bounds__(256) void fused_naive_kernel(
    const float* __restrict__ x, const float* __restrict__ w1,
    const float* __restrict__ b1, const float* __restrict__ w2,
    const float* __restrict__ b2, const float* __restrict__ probs,
    float* __restrict__ y)
{
  __shared__ float xs[8][1024];
  __shared__ float gs[8][64];
  __shared__ float ps[8];
  const int tid = threadIdx.x;
  const int t0 = blockIdx.x * 8;
  const size_t DH = (size_t)1024 * 4096;
  const int tt = tid >> 5;
  const int d0 = (tid & 31) * 32;
  float acc[32];
#pragma unroll
  for (int i = 0; i < 32; ++i) acc[i] = 0.f;
  {
    const f32x4* xsrc = (const f32x4*)(x + (size_t)t0 * 1024);
    f32x4* xdst = (f32x4*)&xs[0][0];
    for (int i = tid; i < 2048; i += 256) xdst[i] = xsrc[i];
  }
  const int wv = tid >> 6;
  const int hl = tid & 63;
  for (int e = 0; e < 8; ++e) {
    if (tid < 8) ps[tid] = probs[(size_t)(t0 + tid) * 8 + e];
    __syncthreads();
    for (int hc = 0; hc < 4096; hc += 64) {
      float a0 = 0.f, a1 = 0.f;
      const float* w1p = w1 + (size_t)e * DH + hc + hl;
      for (int d = 0; d < 1024; ++d) {
        float wvv = w1p[(size_t)d * 4096];
        a0 += xs[wv * 2 + 0][d] * wvv;
        a1 += xs[wv * 2 + 1][d] * wvv;
      }
      __syncthreads();
      gs[wv * 2 + 0][hl] =
          ps[wv * 2 + 0] * gelu_f(a0 + b1[(size_t)e * 4096 + hc + hl]);
      gs[wv * 2 + 1][hl] =
          ps[wv * 2 + 1] * gelu_f(a1 + b1[(size_t)e * 4096 + hc + hl]);
      __syncthreads();
      const float* w2p = w2 + (size_t)e * DH + (size_t)hc * 1024 + d0;
      for (int hh = 0; hh < 64; ++hh) {
        float g = gs[tt][hh];
#pragma unroll
        for (int jb = 0; jb < 8; ++jb) {
          f32x4 w4 = *(const f32x4*)(w2p + (size_t)hh * 1024 + jb * 4);
#pragma unroll
          for (int j2 = 0; j2 < 4; ++j2) acc[jb * 4 + j2] += g * w4[j2];
        }
      }
    }
#pragma unroll
    for (int j = 0; j < 32; ++j)
      acc[j] += ps[tt] * b2[(size_t)e * 1024 + d0 + j];
    __syncthreads();
  }
  float* yp = y + (size_t)(t0 + tt) * 1024 + d0;
#pragma unroll
  for (int jb = 0; jb < 8; ++jb) {
    f32x4 o = {acc[jb * 4], acc[jb * 4 + 1], acc[jb * 4 + 2], acc[jb * 4 + 3]};
    *(f32x4*)(yp + jb * 4) = o;
  }
}

// ---------------------------------------------------------------------------
extern "C" void kernel_launch(void* const* d_in, const int* in_sizes, int n_in,
                              void* d_out, int out_size, void* d_ws,
                              size_t ws_size, hipStream_t stream)
{
  const float* x  = (const float*)d_in[0];  // [2048,1024]
  const float* rw = (const float*)d_in[1];  // [1024,8]
  const float* rb = (const float*)d_in[2];  // [8]
  const float* w1 = (const float*)d_in[3];  // [8,1024,4096]
  const float* b1 = (const float*)d_in[4];  // [8,4096]
  const float* w2 = (const float*)d_in[5];  // [8,4096,1024]
  const float* b2 = (const float*)d_in[6];  // [8,1024]
  float* y = (float*)d_out;                   // [2048,1024]
  float* probs_out = y + (size_t)2048 * 1024; // [2048,8]

  const size_t DH = (size_t)1024 * 4096;
  const size_t BASE = (64 << 10) + (size_t)2048 * 1024 * 2;      // PT | xb
  const size_t TA = BASE + 8 * DH * 2 + (size_t)2048 * 32768 * 2;  // ~196.2MB
  const size_t TB = BASE + DH * 2 + (size_t)2048 * 4096 * 2;       // ~28.2MB

  char* ws = (char*)d_ws;
  float* PT = (float*)ws;
  __bf16* xb = (__bf16*)(ws + (64 << 10));
  __bf16* WT = (__bf16*)(ws + BASE);

  if (ws_size >= TA) {
    pre_kernel<<<512, 256, 0, stream>>>(x, rw, rb, b2, PT, probs_out, xb, y);
    __bf16* Hs = WT + 8 * DH;       // [2048][32768] bf16
    transconv_kernel<<<dim3(16, 16, 8), 256, 0, stream>>>(
        w1, WT, 1024, 4096, 1024, DH);
    gemm1_kernel<<<dim3(8, 16, 8), 512, 0, stream>>>(xb, WT, b1, PT, Hs,
                                                     32768, 0, DH);
    transconv_kernel<<<dim3(64, 4, 8), 256, 0, stream>>>(
        w2, WT, 4096, 1024, 32768, 4096);
    gemm2_kernel<<<dim3(8, 4, 8), 512, 0, stream>>>(Hs, WT, y, 32768,
                                                    32768, 4096, 4096);
  } else if (ws_size >= TB) {
    pre_kernel<<<512, 256, 0, stream>>>(x, rw, rb, b2, PT, probs_out, xb, y);
    __bf16* HsE = WT + DH;          // 16 MB
    for (int e = 0; e < 8; ++e) {
      transconv_kernel<<<dim3(16, 16, 1), 256, 0, stream>>>(
          w1 + (size_t)e * DH, WT, 1024, 4096, 1024, 0);
      gemm1_kernel<<<dim3(8, 16, 1), 512, 0, stream>>>(xb, WT, b1, PT, HsE,
                                                       4096, e, 0);
      transconv_kernel<<<dim3(64, 4, 1), 256, 0, stream>>>(
          w2 + (size_t)e * DH, WT, 4096, 1024, 4096, 0);
      gemm2_kernel<<<dim3(8, 4, 4), 512, 0, stream>>>(HsE, WT, y, 4096,
                                                      4096, 1024, 1024);
    }
  } else {
    router_kernel<<<512, 256, 0, stream>>>(x, rw, rb, probs_out);
    fused_naive_kernel<<<256, 256, 0, stream>>>(x, w1, b1, w2, b2, probs_out,
                                                y);
  }
}